// Round 10
// baseline (101.550 us; speedup 1.0000x reference)
//
#include <hip/hip_runtime.h>
#include <math.h>

#define EPS 1e-5f
#define B_ 8
#define C_ 512
#define S_ 2048
#define IC_ 64
#define IS_ 256
#define DS_ 32

// ws layout (float units). theta/phi/A are bf16 hi/lo PLANES; g is bf16.
// ws[0..31] = int counters for k2's fused reduction (zeroed by k1).
#define SZ_T      (S_*C_/2)                  // one [S][C] bf16 plane = 524288
#define OFF_THT_H 1024
#define OFF_THT_L (OFF_THT_H + SZ_T)
#define OFF_PHT_H (OFF_THT_L + SZ_T)
#define OFF_PHT_L (OFF_PHT_H + SZ_T)
#define SZ_A      (2*IS_*C_/2)               // 131072
#define OFF_A_H   (OFF_PHT_L + SZ_T)
#define OFF_A_L   (OFF_A_H + SZ_A)
#define OFF_G     (OFF_A_L + SZ_A)           // bf16 g [8][256][2048] = 2M floats
#define OFF_AP    OFF_G                      // fp32 partials [8][2][256][512] = 2M floats (exact alias)

using short8 = __attribute__((ext_vector_type(8))) short;
using sh4    = __attribute__((ext_vector_type(4))) short;
using f32x4  = __attribute__((ext_vector_type(4))) float;

__device__ __forceinline__ short f2bf(float f) {
  union { float f; unsigned u; } v; v.f = f;
  unsigned r = v.u + 0x7fffu + ((v.u >> 16) & 1u);
  return (short)(r >> 16);
}
__device__ __forceinline__ float bf2f(short h) {
  union { unsigned u; float f; } v;
  v.u = ((unsigned)(unsigned short)h) << 16;
  return v.f;
}
// split f into hi+lo bf16 pair: f = hi + lo + O(2^-18 * f)
__device__ __forceinline__ void split8arr(const float* f, short8& hi, short8& lo) {
#pragma unroll
  for (int e = 0; e < 8; ++e) {
    short h = f2bf(f[e]);
    hi[e] = h;
    lo[e] = f2bf(f[e] - bf2f(h));
  }
}
__device__ __forceinline__ void split44(float4 a, float4 b, short8& hi, short8& lo) {
  float f[8] = {a.x, a.y, a.z, a.w, b.x, b.y, b.z, b.w};
  split8arr(f, hi, lo);
}

// --------------- k1: theta/phi = relu(bn(W @ x)), split-bf16 MFMA 16x16x32
// grid (32 s-tiles, 8 b), block 512 = 8 waves = (mat, s-quarter16).
// Outputs hi/lo bf16 planes. Also zeroes k2's reduction counters.
__global__ __launch_bounds__(512) void k1_mfma(
    const float* __restrict__ x, const float* __restrict__ Wt,
    const float* __restrict__ Wp,
    const float* __restrict__ tg, const float* __restrict__ tb,
    const float* __restrict__ tm, const float* __restrict__ tv,
    const float* __restrict__ pg, const float* __restrict__ pb,
    const float* __restrict__ pm, const float* __restrict__ pv,
    float* __restrict__ ws) {
  __shared__ short xh[64 * 72], xlo[64 * 72];       // [s][k]
  __shared__ short wh[2][64 * 72], wlo[2][64 * 72]; // [mat][m][k]
  __shared__ float cst_l[256];
  const int tid  = threadIdx.x;
  const int lane = tid & 63;
  const int wv   = tid >> 6;          // 0..7
  const int mat  = wv >> 2, sh = wv & 3;
  const int s0   = blockIdx.x * 64;
  const int b    = blockIdx.y;
  const float* xb = x + (size_t)b * C_ * S_;
  const int xs = tid & 63;             // staging: s-lane
  const int xo = tid >> 6;             // staging: octet 0..7

  if (blockIdx.x == 0 && blockIdx.y == 0 && tid < 32)
    ((int*)ws)[tid] = 0;               // k2 group counters

  if (tid < 64) {
    float a = tg[tid] * rsqrtf(tv[tid] + EPS);
    cst_l[tid] = a; cst_l[64 + tid] = tb[tid] - tm[tid] * a;
    float ap = pg[tid] * rsqrtf(pv[tid] + EPS);
    cst_l[128 + tid] = ap; cst_l[192 + tid] = pb[tid] - pm[tid] * ap;
  }

  float  xr[8];
  float4 wr[2][2];
  f32x4  acc[4];
#pragma unroll
  for (int i = 0; i < 4; ++i) acc[i] = (f32x4){0.f, 0.f, 0.f, 0.f};

#define K1_PF(KC) do {                                                        \
    _Pragma("unroll")                                                         \
    for (int e = 0; e < 8; ++e)                                               \
      xr[e] = xb[(size_t)((KC) + xo * 8 + e) * S_ + s0 + xs];                 \
    _Pragma("unroll")                                                         \
    for (int p = 0; p < 2; ++p) {                                             \
      int q = tid + p * 512;                                                  \
      int mq = q >> 9, m = (q >> 3) & 63, oct = q & 7;                        \
      const float* Wm = mq ? Wp : Wt;                                         \
      wr[p][0] = *(const float4*)&Wm[(size_t)m * C_ + (KC) + oct * 8];        \
      wr[p][1] = *(const float4*)&Wm[(size_t)m * C_ + (KC) + oct * 8 + 4];    \
    } } while (0)

  K1_PF(0);
  for (int c = 0; c < 8; ++c) {
    if (c) __syncthreads();
    {
      short8 hi, lo; split8arr(xr, hi, lo);
      *(short8*)&xh[xs * 72 + xo * 8]  = hi;
      *(short8*)&xlo[xs * 72 + xo * 8] = lo;
    }
#pragma unroll
    for (int p = 0; p < 2; ++p) {
      int q = tid + p * 512;
      int mq = q >> 9, m = (q >> 3) & 63, oct = q & 7;
      short8 hi, lo; split44(wr[p][0], wr[p][1], hi, lo);
      *(short8*)&wh[mq][m * 72 + oct * 8]  = hi;
      *(short8*)&wlo[mq][m * 72 + oct * 8] = lo;
    }
    __syncthreads();
    if (c < 7) K1_PF((c + 1) * 64);
#pragma unroll
    for (int ks = 0; ks < 2; ++ks) {
      const int ko = ks * 32 + ((lane >> 4) << 3);
      short8 bh, bl, ah[4], al[4];
      {
        int r = (sh * 16 + (lane & 15)) * 72 + ko;
        bh = *(const short8*)&xh[r];
        bl = *(const short8*)&xlo[r];
      }
#pragma unroll
      for (int mi = 0; mi < 4; ++mi) {
        int r = (mi * 16 + (lane & 15)) * 72 + ko;
        ah[mi] = *(const short8*)&wh[mat][r];
        al[mi] = *(const short8*)&wlo[mat][r];
      }
#pragma unroll
      for (int mi = 0; mi < 4; ++mi) {
        acc[mi] = __builtin_amdgcn_mfma_f32_16x16x32_bf16(ah[mi], bh, acc[mi], 0, 0, 0);
        acc[mi] = __builtin_amdgcn_mfma_f32_16x16x32_bf16(ah[mi], bl, acc[mi], 0, 0, 0);
        acc[mi] = __builtin_amdgcn_mfma_f32_16x16x32_bf16(al[mi], bh, acc[mi], 0, 0, 0);
      }
    }
  }
#undef K1_PF
  const float* ac = &cst_l[mat * 128];
  short* outH = (short*)(ws + (mat ? OFF_PHT_H : OFF_THT_H));
  short* outL = (short*)(ws + (mat ? OFF_PHT_L : OFF_THT_L));
  const int s = s0 + sh * 16 + (lane & 15);
#pragma unroll
  for (int mi = 0; mi < 4; ++mi) {
    const int m = mi * 16 + ((lane >> 4) << 2);
    float4 sc4 = *(const float4*)&ac[m];
    float4 bi4 = *(const float4*)&ac[64 + m];
    float vals[4];
    vals[0] = fmaxf(sc4.x * acc[mi][0] + bi4.x, 0.f);
    vals[1] = fmaxf(sc4.y * acc[mi][1] + bi4.y, 0.f);
    vals[2] = fmaxf(sc4.z * acc[mi][2] + bi4.z, 0.f);
    vals[3] = fmaxf(sc4.w * acc[mi][3] + bi4.w, 0.f);
    sh4 qh, ql;
#pragma unroll
    for (int e = 0; e < 4; ++e) {
      short h = f2bf(vals[e]);
      qh[e] = h; ql[e] = f2bf(vals[e] - bf2f(h));
    }
    size_t ix = (size_t)s * C_ + b * IC_ + m;
    *(sh4*)&outH[ix] = qh;
    *(sh4*)&outL[ix] = ql;
  }
}

// ---- k2: Ap[part][mat][o][n] = Wgg[o, mat*S + t] @ (mat? thetaT : phiT)[t][n]
// grid (8 n-tiles, 2 o-tiles, mat*8+part), block 256 = 4 waves (o-quarter).
// split-K 8. Fused reduction: last block of each 8-part group sums partials
// (fixed order -> deterministic) and writes A hi/lo planes.
__global__ __launch_bounds__(256) void k2_mfma(
    const float* __restrict__ Wgg, float* __restrict__ ws,
    float* __restrict__ Ap) {
  __shared__ short nh[64 * 72], nlo[64 * 72];     // [n][t]
  __shared__ short oh[128 * 72], olo[128 * 72];   // [o][t]
  __shared__ int lastFlag;
  const int tid  = threadIdx.x;
  const int lane = tid & 63;
  const int wv   = tid >> 6;
  const int n0    = blockIdx.x * 64;
  const int o_blk = blockIdx.y * 128;
  const int mat   = blockIdx.z >> 3;
  const int part  = blockIdx.z & 7;
  const int t0 = part * 256;
  const short* BmH = (const short*)(ws + (mat ? OFF_THT_H : OFF_PHT_H));
  const short* BmL = (const short*)(ws + (mat ? OFF_THT_L : OFF_PHT_L));
  const int xs = tid & 63;
  const int xo = tid >> 6;

  short8 arh[2], arl[2];
  float4 br[4][2];
  f32x4  acc[4][2];
#pragma unroll
  for (int i = 0; i < 4; ++i)
#pragma unroll
    for (int j = 0; j < 2; ++j) acc[i][j] = (f32x4){0.f, 0.f, 0.f, 0.f};

#define K2_PF(KC) do {                                                        \
    _Pragma("unroll")                                                         \
    for (int h = 0; h < 2; ++h) {                                             \
      int oct = xo + h * 4;                                                   \
      _Pragma("unroll")                                                       \
      for (int e = 0; e < 8; ++e) {                                           \
        size_t ix = (size_t)(t0 + (KC) + oct * 8 + e) * C_ + n0 + xs;         \
        arh[h][e] = BmH[ix];                                                  \
        arl[h][e] = BmL[ix];                                                  \
      }                                                                       \
    }                                                                         \
    _Pragma("unroll")                                                         \
    for (int p = 0; p < 4; ++p) {                                             \
      int q = tid + p * 256;                                                  \
      int o = q >> 3, oct = q & 7;                                            \
      const float* src = &Wgg[(size_t)(o_blk + o) * (2 * S_) + mat * S_ +     \
                              t0 + (KC) + oct * 8];                           \
      br[p][0] = *(const float4*)src;                                         \
      br[p][1] = *(const float4*)(src + 4);                                   \
    } } while (0)

  K2_PF(0);
  for (int c = 0; c < 4; ++c) {
    if (c) __syncthreads();
#pragma unroll
    for (int h = 0; h < 2; ++h) {
      int oct = xo + h * 4;
      *(short8*)&nh[xs * 72 + oct * 8]  = arh[h];
      *(short8*)&nlo[xs * 72 + oct * 8] = arl[h];
    }
#pragma unroll
    for (int p = 0; p < 4; ++p) {
      int q = tid + p * 256;
      int o = q >> 3, oct = q & 7;
      short8 hi, lo; split44(br[p][0], br[p][1], hi, lo);
      *(short8*)&oh[o * 72 + oct * 8]  = hi;
      *(short8*)&olo[o * 72 + oct * 8] = lo;
    }
    __syncthreads();
    if (c < 3) K2_PF((c + 1) * 64);
#pragma unroll
    for (int ks = 0; ks < 2; ++ks) {
      const int ko = ks * 32 + ((lane >> 4) << 3);
      short8 ah[4], al[4], bh[2], bl[2];
#pragma unroll
      for (int ni = 0; ni < 4; ++ni) {
        int r = (ni * 16 + (lane & 15)) * 72 + ko;
        ah[ni] = *(const short8*)&nh[r];
        al[ni] = *(const short8*)&nlo[r];
      }
#pragma unroll
      for (int oj = 0; oj < 2; ++oj) {
        int r = (wv * 32 + oj * 16 + (lane & 15)) * 72 + ko;
        bh[oj] = *(const short8*)&oh[r];
        bl[oj] = *(const short8*)&olo[r];
      }
#pragma unroll
      for (int ni = 0; ni < 4; ++ni)
#pragma unroll
        for (int oj = 0; oj < 2; ++oj) {
          acc[ni][oj] = __builtin_amdgcn_mfma_f32_16x16x32_bf16(
              ah[ni], bh[oj], acc[ni][oj], 0, 0, 0);
          acc[ni][oj] = __builtin_amdgcn_mfma_f32_16x16x32_bf16(
              ah[ni], bl[oj], acc[ni][oj], 0, 0, 0);
          acc[ni][oj] = __builtin_amdgcn_mfma_f32_16x16x32_bf16(
              al[ni], bh[oj], acc[ni][oj], 0, 0, 0);
        }
    }
  }
#undef K2_PF
#pragma unroll
  for (int ni = 0; ni < 4; ++ni) {
    const int nq = n0 + ni * 16 + ((lane >> 4) << 2);
#pragma unroll
    for (int oj = 0; oj < 2; ++oj) {
      int o = o_blk + wv * 32 + oj * 16 + (lane & 15);
      float4 q;
      q.x = acc[ni][oj][0]; q.y = acc[ni][oj][1];
      q.z = acc[ni][oj][2]; q.w = acc[ni][oj][3];
      *(float4*)&Ap[((size_t)(part * 2 + mat) * IS_ + o) * C_ + nq] = q;
    }
  }
  // ---- fused reduction: last block of the (mat, o_blk, n0) group
  __threadfence();
  if (tid == 0) {
    int grp = mat * 16 + blockIdx.y * 8 + blockIdx.x;   // 0..31
    int old = atomicAdd((int*)ws + grp, 1);
    lastFlag = (old == 7);
  }
  __syncthreads();
  if (lastFlag) {
    __threadfence();   // acquire: other blocks' partials now visible
    short* AH = (short*)(ws + OFF_A_H);
    short* AL = (short*)(ws + OFF_A_L);
    for (int e = tid; e < 128 * 64; e += 256) {
      int o = o_blk + (e >> 6), n = n0 + (e & 63);
      float s = 0.f;
#pragma unroll
      for (int p = 0; p < 8; ++p)
        s += Ap[((size_t)(p * 2 + mat) * IS_ + o) * C_ + n];
      short h = f2bf(s);
      size_t ix = ((size_t)mat * IS_ + o) * C_ + n;
      AH[ix] = h;
      AL[ix] = f2bf(s - bf2f(h));
    }
  }
}

// -------- k3: g[b][o][s] = relu(bn(A0 @ thetaT_b + A1 @ phiT_b)), split-bf16
// grid (32 s-tiles, 2 o-tiles, 8 b), block 256 = 4 waves (o-quarter).
// Staging is pure short8 loads from bf16 planes. g written as single bf16.
__global__ __launch_bounds__(256) void k3_mfma(
    float* __restrict__ ws,
    const float* __restrict__ gg, const float* __restrict__ gb,
    const float* __restrict__ gm, const float* __restrict__ gv) {
  __shared__ short th[64 * 72], tlo[64 * 72];     // [s][c]
  __shared__ short ohh[128 * 72], olo[128 * 72];  // [o][c]
  __shared__ float cstg[512];
  const int tid  = threadIdx.x;
  const int lane = tid & 63;
  const int wv   = tid >> 6;
  const int s0    = blockIdx.x * 64;
  const int o_blk = blockIdx.y * 128;
  const int b     = blockIdx.z;
  const short* AH = (const short*)(ws + OFF_A_H);
  const short* AL = (const short*)(ws + OFF_A_L);

  {
    float a = gg[tid] * rsqrtf(gv[tid] + EPS);
    cstg[tid] = a; cstg[256 + tid] = gb[tid] - gm[tid] * a;
  }

  short8 arh[2], arl[2];
  short8 brh[4], brl[4];
  f32x4  acc[4][2];
#pragma unroll
  for (int i = 0; i < 4; ++i)
#pragma unroll
    for (int j = 0; j < 2; ++j) acc[i][j] = (f32x4){0.f, 0.f, 0.f, 0.f};

#define K3_PF(MAT) do {                                                       \
    const short* TH = (const short*)(ws + ((MAT) ? OFF_PHT_H : OFF_THT_H));   \
    const short* TL = (const short*)(ws + ((MAT) ? OFF_PHT_L : OFF_THT_L));   \
    _Pragma("unroll")                                                         \
    for (int p = 0; p < 2; ++p) {                                             \
      int q = tid + p * 256;                                                  \
      int sl = q >> 3, oct = q & 7;                                           \
      size_t ix = (size_t)(s0 + sl) * C_ + b * IC_ + oct * 8;                 \
      arh[p] = *(const short8*)&TH[ix];                                       \
      arl[p] = *(const short8*)&TL[ix];                                       \
    }                                                                         \
    _Pragma("unroll")                                                         \
    for (int p = 0; p < 4; ++p) {                                             \
      int q = tid + p * 256;                                                  \
      int o = q >> 3, oct = q & 7;                                            \
      size_t ix = ((size_t)(MAT) * IS_ + o_blk + o) * C_ + b * IC_ + oct * 8; \
      brh[p] = *(const short8*)&AH[ix];                                       \
      brl[p] = *(const short8*)&AL[ix];                                       \
    } } while (0)

  K3_PF(0);
  for (int c = 0; c < 2; ++c) {
    if (c) __syncthreads();
#pragma unroll
    for (int p = 0; p < 2; ++p) {
      int q = tid + p * 256;
      int sl = q >> 3, oct = q & 7;
      *(short8*)&th[sl * 72 + oct * 8]  = arh[p];
      *(short8*)&tlo[sl * 72 + oct * 8] = arl[p];
    }
#pragma unroll
    for (int p = 0; p < 4; ++p) {
      int q = tid + p * 256;
      int o = q >> 3, oct = q & 7;
      *(short8*)&ohh[o * 72 + oct * 8] = brh[p];
      *(short8*)&olo[o * 72 + oct * 8] = brl[p];
    }
    __syncthreads();
    if (c < 1) K3_PF(1);
#pragma unroll
    for (int ks = 0; ks < 2; ++ks) {
      const int ko = ks * 32 + ((lane >> 4) << 3);
      short8 ah[4], al[4], bh[2], bl[2];
#pragma unroll
      for (int si = 0; si < 4; ++si) {
        int r = (si * 16 + (lane & 15)) * 72 + ko;
        ah[si] = *(const short8*)&th[r];
        al[si] = *(const short8*)&tlo[r];
      }
#pragma unroll
      for (int oj = 0; oj < 2; ++oj) {
        int r = (wv * 32 + oj * 16 + (lane & 15)) * 72 + ko;
        bh[oj] = *(const short8*)&ohh[r];
        bl[oj] = *(const short8*)&olo[r];
      }
#pragma unroll
      for (int si = 0; si < 4; ++si)
#pragma unroll
        for (int oj = 0; oj < 2; ++oj) {
          acc[si][oj] = __builtin_amdgcn_mfma_f32_16x16x32_bf16(
              ah[si], bh[oj], acc[si][oj], 0, 0, 0);
          acc[si][oj] = __builtin_amdgcn_mfma_f32_16x16x32_bf16(
              ah[si], bl[oj], acc[si][oj], 0, 0, 0);
          acc[si][oj] = __builtin_amdgcn_mfma_f32_16x16x32_bf16(
              al[si], bh[oj], acc[si][oj], 0, 0, 0);
        }
    }
  }
#undef K3_PF
  short* g = (short*)(ws + OFF_G);
#pragma unroll
  for (int oj = 0; oj < 2; ++oj) {
    int o = o_blk + wv * 32 + oj * 16 + (lane & 15);
    float sc = cstg[o], bi = cstg[256 + o];
#pragma unroll
    for (int si = 0; si < 4; ++si) {
      int sq = s0 + si * 16 + ((lane >> 4) << 2);
      sh4 q4;
      q4[0] = f2bf(fmaxf(sc * acc[si][oj][0] + bi, 0.f));
      q4[1] = f2bf(fmaxf(sc * acc[si][oj][1] + bi, 0.f));
      q4[2] = f2bf(fmaxf(sc * acc[si][oj][2] + bi, 0.f));
      q4[3] = f2bf(fmaxf(sc * acc[si][oj][3] + bi, 0.f));
      *(sh4*)&g[((size_t)b * IS_ + o) * S_ + sq] = q4;
    }
  }
}

// --- k4: y=relu(bn(W1@g)); ys=bn(W2@y); gate=sigmoid; out = x*gate (fused)
// grid (64 s-tiles of 32, 8 b), 512 threads, ~56KB LDS -> 2 blocks/CU.
__global__ __launch_bounds__(512) void k4_fused(
    const float* __restrict__ x, const float* __restrict__ W1,
    const float* __restrict__ W2,
    const float* __restrict__ w1g, const float* __restrict__ w1b,
    const float* __restrict__ w1m, const float* __restrict__ w1v,
    const float* __restrict__ w2g, const float* __restrict__ w2b,
    const float* __restrict__ w2m, const float* __restrict__ w2v,
    const float* __restrict__ ws, float* __restrict__ out) {
  __shared__ float lds_g[128 * 36];    // 18.4 KB
  __shared__ float lds_w[32 * 260];    // 33.3 KB
  __shared__ float lds_y[32 * 33];     // 4.2 KB
  __shared__ float lds_gate[32];
  __shared__ float wc[66];             // w1 scale[32], w1 bias[32], w2 s/b
  const int tid = threadIdx.x;
  const int s0  = blockIdx.x * 32;
  const int b   = blockIdx.y;
  const int s   = tid & 31;
  const int og  = tid >> 5;            // 16 groups x 2 y-rows
  const short* gsrc = (const short*)(ws + OFF_G) + (size_t)b * IS_ * S_;

  if (tid < 32) {
    float a = w1g[tid] * rsqrtf(w1v[tid] + EPS);
    wc[tid] = a; wc[32 + tid] = w1b[tid] - w1m[tid] * a;
  } else if (tid == 32) {
    float a = w2g[0] * rsqrtf(w2v[0] + EPS);
    wc[64] = a; wc[65] = w2b[0] - w2m[0] * a;
  }
  // stage W1 [32][256] -> lds_w pitch 260 (one-time, 4 float4/thread)
#pragma unroll
  for (int j = 0; j < 4; ++j) {
    int f = tid + j * 512;             // 0..2047 float4 slots (32 rows x 64)
    int row = f >> 6, c4 = f & 63;
    *(float4*)&lds_w[row * 260 + c4 * 4] =
        *(const float4*)&W1[(size_t)row * IS_ + c4 * 4];
  }
  float acc[2] = {};

  for (int half = 0; half < 2; ++half) {
    __syncthreads();
    {
      int row = tid >> 2, oct = tid & 3;   // 128 rows x 4 octs = 512
      short8 v = *(const short8*)&gsrc[(size_t)(half * 128 + row) * S_ +
                                       s0 + oct * 8];
      float4 f0 = make_float4(bf2f(v[0]), bf2f(v[1]), bf2f(v[2]), bf2f(v[3]));
      float4 f1 = make_float4(bf2f(v[4]), bf2f(v[5]), bf2f(v[6]), bf2f(v[7]));
      *(float4*)&lds_g[row * 36 + oct * 8]     = f0;
      *(float4*)&lds_g[row * 36 + oct * 8 + 4] = f1;
    }
    __syncthreads();
#pragma unroll
    for (int c4 = 0; c4 < 32; ++c4) {
      float g0 = lds_g[(c4 * 4 + 0) * 36 + s];
      float g1 = lds_g[(c4 * 4 + 1) * 36 + s];
      float g2 = lds_g[(c4 * 4 + 2) * 36 + s];
      float g3 = lds_g[(c4 * 4 + 3) * 36 + s];
#pragma unroll
      for (int j = 0; j < 2; ++j) {
        const float4 w = *(const float4*)&lds_w[(og * 2 + j) * 260 +
                                                half * 128 + c4 * 4];
        acc[j] += g0 * w.x + g1 * w.y + g2 * w.z + g3 * w.w;
      }
    }
  }
#pragma unroll
  for (int j = 0; j < 2; ++j) {
    int o = og * 2 + j;
    float v = wc[o] * acc[j] + wc[32 + o];
    lds_y[o * 33 + s] = v > 0.f ? v : 0.f;
  }
  __syncthreads();
  if (tid < 32) {
    float sum = 0.f;
#pragma unroll
    for (int c = 0; c < 32; ++c) sum += W2[c] * lds_y[c * 33 + tid];
    float ys = wc[64] * sum + wc[65];
    lds_gate[tid] = 1.f / (1.f + expf(-ys));
  }
  __syncthreads();
  // stream: out[b][ch][s0..s0+31] = x * gate. 8-lane groups own one channel
  // row (128 B contiguous); wave covers 8 channels; 8 iters.
  const int l = tid & 63, w = tid >> 6;
  const int q4 = (l & 7) * 4;          // s-offset within tile
  const int cl = w * 8 + (l >> 3);     // channel-in-iteration 0..63
  const float4 gv = *(const float4*)&lds_gate[q4];
  const float* xb = x + (size_t)b * C_ * S_ + s0;
  float* ob = out + (size_t)b * C_ * S_ + s0;
#pragma unroll
  for (int it = 0; it < 8; ++it) {
    int ch = it * 64 + cl;
    const float4 xv = *(const float4*)&xb[(size_t)ch * S_ + q4];
    float4 ov;
    ov.x = xv.x * gv.x; ov.y = xv.y * gv.y;
    ov.z = xv.z * gv.z; ov.w = xv.w * gv.w;
    *(float4*)&ob[(size_t)ch * S_ + q4] = ov;
  }
}

// ---------------------------------------------------------------------------
extern "C" void kernel_launch(void* const* d_in, const int* in_sizes, int n_in,
                              void* d_out, int out_size, void* d_ws, size_t ws_size,
                              hipStream_t stream) {
  const float* x   = (const float*)d_in[0];
  const float* Wt  = (const float*)d_in[1];
  const float* tg  = (const float*)d_in[2];
  const float* tb  = (const float*)d_in[3];
  const float* tm  = (const float*)d_in[4];
  const float* tv  = (const float*)d_in[5];
  const float* Wp  = (const float*)d_in[6];
  const float* pg  = (const float*)d_in[7];
  const float* pb  = (const float*)d_in[8];
  const float* pm  = (const float*)d_in[9];
  const float* pv  = (const float*)d_in[10];
  const float* Wgg = (const float*)d_in[11];
  const float* ggg = (const float*)d_in[12];
  const float* ggb = (const float*)d_in[13];
  const float* ggm = (const float*)d_in[14];
  const float* ggv = (const float*)d_in[15];
  const float* W1  = (const float*)d_in[16];
  const float* w1g = (const float*)d_in[17];
  const float* w1b = (const float*)d_in[18];
  const float* w1m = (const float*)d_in[19];
  const float* w1v = (const float*)d_in[20];
  const float* W2  = (const float*)d_in[21];
  const float* w2g = (const float*)d_in[22];
  const float* w2b = (const float*)d_in[23];
  const float* w2m = (const float*)d_in[24];
  const float* w2v = (const float*)d_in[25];
  float* ws  = (float*)d_ws;
  float* out = (float*)d_out;

  k1_mfma<<<dim3(32, 8), 512, 0, stream>>>(
      x, Wt, Wp, tg, tb, tm, tv, pg, pb, pm, pv, ws);
  k2_mfma<<<dim3(8, 2, 16), 256, 0, stream>>>(Wgg, ws, ws + OFF_AP);
  k3_mfma<<<dim3(32, 2, 8), 256, 0, stream>>>(ws, ggg, ggb, ggm, ggv);
  k4_fused<<<dim3(64, 8), 512, 0, stream>>>(
      x, W1, W2, w1g, w1b, w1m, w1v, w2g, w2b, w2m, w2v, ws, out);
}

// Round 11
// 67.221 us; speedup vs baseline: 1.5107x; 1.5107x over previous
//
#include <hip/hip_runtime.h>
#include <math.h>

#define EPS 1e-5f
#define B_ 8
#define C_ 512
#define S_ 2048
#define IC_ 64
#define IS_ 256
#define DS_ 32

// ws layout (float units). theta/phi/A are bf16 hi/lo PLANES; g is bf16.
#define SZ_T      (S_*C_/2)                  // one [S][C] bf16 plane = 524288
#define OFF_THT_H 1024
#define OFF_THT_L (OFF_THT_H + SZ_T)
#define OFF_PHT_H (OFF_THT_L + SZ_T)
#define OFF_PHT_L (OFF_PHT_H + SZ_T)
#define SZ_A      (2*IS_*C_/2)               // 131072
#define OFF_A_H   (OFF_PHT_L + SZ_T)
#define OFF_A_L   (OFF_A_H + SZ_A)
#define OFF_G     (OFF_A_L + SZ_A)           // bf16 g [8][256][2048] = 2M floats
#define OFF_AP    OFF_G                      // fp32 partials [8][2][256][512] = 2M floats (exact alias)

using short8 = __attribute__((ext_vector_type(8))) short;
using sh4    = __attribute__((ext_vector_type(4))) short;
using f32x4  = __attribute__((ext_vector_type(4))) float;

__device__ __forceinline__ short f2bf(float f) {
  union { float f; unsigned u; } v; v.f = f;
  unsigned r = v.u + 0x7fffu + ((v.u >> 16) & 1u);
  return (short)(r >> 16);
}
__device__ __forceinline__ float bf2f(short h) {
  union { unsigned u; float f; } v;
  v.u = ((unsigned)(unsigned short)h) << 16;
  return v.f;
}
// split f into hi+lo bf16 pair: f = hi + lo + O(2^-18 * f)
__device__ __forceinline__ void split8arr(const float* f, short8& hi, short8& lo) {
#pragma unroll
  for (int e = 0; e < 8; ++e) {
    short h = f2bf(f[e]);
    hi[e] = h;
    lo[e] = f2bf(f[e] - bf2f(h));
  }
}
__device__ __forceinline__ void split44(float4 a, float4 b, short8& hi, short8& lo) {
  float f[8] = {a.x, a.y, a.z, a.w, b.x, b.y, b.z, b.w};
  split8arr(f, hi, lo);
}

// --------------- k1: theta/phi = relu(bn(W @ x)), split-bf16 MFMA 16x16x32
// grid (32 s-tiles, 8 b), block 512 = 8 waves = (mat, s-quarter16).
// Outputs hi/lo bf16 planes.
__global__ __launch_bounds__(512) void k1_mfma(
    const float* __restrict__ x, const float* __restrict__ Wt,
    const float* __restrict__ Wp,
    const float* __restrict__ tg, const float* __restrict__ tb,
    const float* __restrict__ tm, const float* __restrict__ tv,
    const float* __restrict__ pg, const float* __restrict__ pb,
    const float* __restrict__ pm, const float* __restrict__ pv,
    float* __restrict__ ws) {
  __shared__ short xh[64 * 72], xlo[64 * 72];       // [s][k]
  __shared__ short wh[2][64 * 72], wlo[2][64 * 72]; // [mat][m][k]
  __shared__ float cst_l[256];
  const int tid  = threadIdx.x;
  const int lane = tid & 63;
  const int wv   = tid >> 6;          // 0..7
  const int mat  = wv >> 2, sh = wv & 3;
  const int s0   = blockIdx.x * 64;
  const int b    = blockIdx.y;
  const float* xb = x + (size_t)b * C_ * S_;
  const int xs = tid & 63;             // staging: s-lane
  const int xo = tid >> 6;             // staging: octet 0..7

  if (tid < 64) {
    float a = tg[tid] * rsqrtf(tv[tid] + EPS);
    cst_l[tid] = a; cst_l[64 + tid] = tb[tid] - tm[tid] * a;
    float ap = pg[tid] * rsqrtf(pv[tid] + EPS);
    cst_l[128 + tid] = ap; cst_l[192 + tid] = pb[tid] - pm[tid] * ap;
  }

  float  xr[8];
  float4 wr[2][2];
  f32x4  acc[4];
#pragma unroll
  for (int i = 0; i < 4; ++i) acc[i] = (f32x4){0.f, 0.f, 0.f, 0.f};

#define K1_PF(KC) do {                                                        \
    _Pragma("unroll")                                                         \
    for (int e = 0; e < 8; ++e)                                               \
      xr[e] = xb[(size_t)((KC) + xo * 8 + e) * S_ + s0 + xs];                 \
    _Pragma("unroll")                                                         \
    for (int p = 0; p < 2; ++p) {                                             \
      int q = tid + p * 512;                                                  \
      int mq = q >> 9, m = (q >> 3) & 63, oct = q & 7;                        \
      const float* Wm = mq ? Wp : Wt;                                         \
      wr[p][0] = *(const float4*)&Wm[(size_t)m * C_ + (KC) + oct * 8];        \
      wr[p][1] = *(const float4*)&Wm[(size_t)m * C_ + (KC) + oct * 8 + 4];    \
    } } while (0)

  K1_PF(0);
  for (int c = 0; c < 8; ++c) {
    if (c) __syncthreads();
    {
      short8 hi, lo; split8arr(xr, hi, lo);
      *(short8*)&xh[xs * 72 + xo * 8]  = hi;
      *(short8*)&xlo[xs * 72 + xo * 8] = lo;
    }
#pragma unroll
    for (int p = 0; p < 2; ++p) {
      int q = tid + p * 512;
      int mq = q >> 9, m = (q >> 3) & 63, oct = q & 7;
      short8 hi, lo; split44(wr[p][0], wr[p][1], hi, lo);
      *(short8*)&wh[mq][m * 72 + oct * 8]  = hi;
      *(short8*)&wlo[mq][m * 72 + oct * 8] = lo;
    }
    __syncthreads();
    if (c < 7) K1_PF((c + 1) * 64);
#pragma unroll
    for (int ks = 0; ks < 2; ++ks) {
      const int ko = ks * 32 + ((lane >> 4) << 3);
      short8 bh, bl, ah[4], al[4];
      {
        int r = (sh * 16 + (lane & 15)) * 72 + ko;
        bh = *(const short8*)&xh[r];
        bl = *(const short8*)&xlo[r];
      }
#pragma unroll
      for (int mi = 0; mi < 4; ++mi) {
        int r = (mi * 16 + (lane & 15)) * 72 + ko;
        ah[mi] = *(const short8*)&wh[mat][r];
        al[mi] = *(const short8*)&wlo[mat][r];
      }
#pragma unroll
      for (int mi = 0; mi < 4; ++mi) {
        acc[mi] = __builtin_amdgcn_mfma_f32_16x16x32_bf16(ah[mi], bh, acc[mi], 0, 0, 0);
        acc[mi] = __builtin_amdgcn_mfma_f32_16x16x32_bf16(ah[mi], bl, acc[mi], 0, 0, 0);
        acc[mi] = __builtin_amdgcn_mfma_f32_16x16x32_bf16(al[mi], bh, acc[mi], 0, 0, 0);
      }
    }
  }
#undef K1_PF
  const float* ac = &cst_l[mat * 128];
  short* outH = (short*)(ws + (mat ? OFF_PHT_H : OFF_THT_H));
  short* outL = (short*)(ws + (mat ? OFF_PHT_L : OFF_THT_L));
  const int s = s0 + sh * 16 + (lane & 15);
#pragma unroll
  for (int mi = 0; mi < 4; ++mi) {
    const int m = mi * 16 + ((lane >> 4) << 2);
    float4 sc4 = *(const float4*)&ac[m];
    float4 bi4 = *(const float4*)&ac[64 + m];
    float vals[4];
    vals[0] = fmaxf(sc4.x * acc[mi][0] + bi4.x, 0.f);
    vals[1] = fmaxf(sc4.y * acc[mi][1] + bi4.y, 0.f);
    vals[2] = fmaxf(sc4.z * acc[mi][2] + bi4.z, 0.f);
    vals[3] = fmaxf(sc4.w * acc[mi][3] + bi4.w, 0.f);
    sh4 qh, ql;
#pragma unroll
    for (int e = 0; e < 4; ++e) {
      short h = f2bf(vals[e]);
      qh[e] = h; ql[e] = f2bf(vals[e] - bf2f(h));
    }
    size_t ix = (size_t)s * C_ + b * IC_ + m;
    *(sh4*)&outH[ix] = qh;
    *(sh4*)&outL[ix] = ql;
  }
}

// ---- k2: Ap[part][mat][o][n] = Wgg[o, mat*S + t] @ (mat? thetaT : phiT)[t][n]
// grid (8 n-tiles, 2 o-tiles, mat*8+part), block 256 = 4 waves (o-quarter).
// split-K 8 (K=256, 4 chunks). B staged directly from bf16 planes (no split).
// NO cross-block sync here — device fences cost an L2 flush per block (r10).
__global__ __launch_bounds__(256) void k2_mfma(
    const float* __restrict__ Wgg, const float* __restrict__ ws,
    float* __restrict__ Ap) {
  __shared__ short nh[64 * 72], nlo[64 * 72];     // [n][t]
  __shared__ short oh[128 * 72], olo[128 * 72];   // [o][t]
  const int tid  = threadIdx.x;
  const int lane = tid & 63;
  const int wv   = tid >> 6;
  const int n0    = blockIdx.x * 64;
  const int o_blk = blockIdx.y * 128;
  const int mat   = blockIdx.z >> 3;
  const int part  = blockIdx.z & 7;
  const int t0 = part * 256;
  const short* BmH = (const short*)(ws + (mat ? OFF_THT_H : OFF_PHT_H));
  const short* BmL = (const short*)(ws + (mat ? OFF_THT_L : OFF_PHT_L));
  const int xs = tid & 63;
  const int xo = tid >> 6;

  short8 arh[2], arl[2];
  float4 br[4][2];
  f32x4  acc[4][2];
#pragma unroll
  for (int i = 0; i < 4; ++i)
#pragma unroll
    for (int j = 0; j < 2; ++j) acc[i][j] = (f32x4){0.f, 0.f, 0.f, 0.f};

#define K2_PF(KC) do {                                                        \
    _Pragma("unroll")                                                         \
    for (int h = 0; h < 2; ++h) {                                             \
      int oct = xo + h * 4;                                                   \
      _Pragma("unroll")                                                       \
      for (int e = 0; e < 8; ++e) {                                           \
        size_t ix = (size_t)(t0 + (KC) + oct * 8 + e) * C_ + n0 + xs;         \
        arh[h][e] = BmH[ix];                                                  \
        arl[h][e] = BmL[ix];                                                  \
      }                                                                       \
    }                                                                         \
    _Pragma("unroll")                                                         \
    for (int p = 0; p < 4; ++p) {                                             \
      int q = tid + p * 256;                                                  \
      int o = q >> 3, oct = q & 7;                                            \
      const float* src = &Wgg[(size_t)(o_blk + o) * (2 * S_) + mat * S_ +     \
                              t0 + (KC) + oct * 8];                           \
      br[p][0] = *(const float4*)src;                                         \
      br[p][1] = *(const float4*)(src + 4);                                   \
    } } while (0)

  K2_PF(0);
  for (int c = 0; c < 4; ++c) {
    if (c) __syncthreads();
#pragma unroll
    for (int h = 0; h < 2; ++h) {
      int oct = xo + h * 4;
      *(short8*)&nh[xs * 72 + oct * 8]  = arh[h];
      *(short8*)&nlo[xs * 72 + oct * 8] = arl[h];
    }
#pragma unroll
    for (int p = 0; p < 4; ++p) {
      int q = tid + p * 256;
      int o = q >> 3, oct = q & 7;
      short8 hi, lo; split44(br[p][0], br[p][1], hi, lo);
      *(short8*)&oh[o * 72 + oct * 8]  = hi;
      *(short8*)&olo[o * 72 + oct * 8] = lo;
    }
    __syncthreads();
    if (c < 3) K2_PF((c + 1) * 64);
#pragma unroll
    for (int ks = 0; ks < 2; ++ks) {
      const int ko = ks * 32 + ((lane >> 4) << 3);
      short8 ah[4], al[4], bh[2], bl[2];
#pragma unroll
      for (int ni = 0; ni < 4; ++ni) {
        int r = (ni * 16 + (lane & 15)) * 72 + ko;
        ah[ni] = *(const short8*)&nh[r];
        al[ni] = *(const short8*)&nlo[r];
      }
#pragma unroll
      for (int oj = 0; oj < 2; ++oj) {
        int r = (wv * 32 + oj * 16 + (lane & 15)) * 72 + ko;
        bh[oj] = *(const short8*)&oh[r];
        bl[oj] = *(const short8*)&olo[r];
      }
#pragma unroll
      for (int ni = 0; ni < 4; ++ni)
#pragma unroll
        for (int oj = 0; oj < 2; ++oj) {
          acc[ni][oj] = __builtin_amdgcn_mfma_f32_16x16x32_bf16(
              ah[ni], bh[oj], acc[ni][oj], 0, 0, 0);
          acc[ni][oj] = __builtin_amdgcn_mfma_f32_16x16x32_bf16(
              ah[ni], bl[oj], acc[ni][oj], 0, 0, 0);
          acc[ni][oj] = __builtin_amdgcn_mfma_f32_16x16x32_bf16(
              al[ni], bh[oj], acc[ni][oj], 0, 0, 0);
        }
    }
  }
#undef K2_PF
#pragma unroll
  for (int ni = 0; ni < 4; ++ni) {
    const int nq = n0 + ni * 16 + ((lane >> 4) << 2);
#pragma unroll
    for (int oj = 0; oj < 2; ++oj) {
      int o = o_blk + wv * 32 + oj * 16 + (lane & 15);
      float4 q;
      q.x = acc[ni][oj][0]; q.y = acc[ni][oj][1];
      q.z = acc[ni][oj][2]; q.w = acc[ni][oj][3];
      *(float4*)&Ap[((size_t)(part * 2 + mat) * IS_ + o) * C_ + nq] = q;
    }
  }
}

// ------------------- k2b: reduce 8 fp32 partials -> A hi/lo bf16 planes
__global__ __launch_bounds__(256) void k2b_reduce(float* __restrict__ ws) {
  int f = blockIdx.x * 256 + threadIdx.x;   // 0..65535 float4 slots
  const float4* ap = (const float4*)(ws + OFF_AP);
  float4 s = ap[f];
#pragma unroll
  for (int p = 1; p < 8; ++p) {
    float4 t = ap[f + p * 65536];
    s.x += t.x; s.y += t.y; s.z += t.z; s.w += t.w;
  }
  float vals[4] = {s.x, s.y, s.z, s.w};
  sh4 h4, l4;
#pragma unroll
  for (int e = 0; e < 4; ++e) {
    short h = f2bf(vals[e]);
    h4[e] = h; l4[e] = f2bf(vals[e] - bf2f(h));
  }
  ((sh4*)(ws + OFF_A_H))[f] = h4;
  ((sh4*)(ws + OFF_A_L))[f] = l4;
}

// -------- k3: g[b][o][s] = relu(bn(A0 @ thetaT_b + A1 @ phiT_b)), split-bf16
// grid (32 s-tiles, 2 o-tiles, 8 b), block 256 = 4 waves (o-quarter).
// Staging is pure short8 loads from bf16 planes. g written as single bf16.
__global__ __launch_bounds__(256) void k3_mfma(
    float* __restrict__ ws,
    const float* __restrict__ gg, const float* __restrict__ gb,
    const float* __restrict__ gm, const float* __restrict__ gv) {
  __shared__ short th[64 * 72], tlo[64 * 72];     // [s][c]
  __shared__ short ohh[128 * 72], olo[128 * 72];  // [o][c]
  __shared__ float cstg[512];
  const int tid  = threadIdx.x;
  const int lane = tid & 63;
  const int wv   = tid >> 6;
  const int s0    = blockIdx.x * 64;
  const int o_blk = blockIdx.y * 128;
  const int b     = blockIdx.z;
  const short* AH = (const short*)(ws + OFF_A_H);
  const short* AL = (const short*)(ws + OFF_A_L);

  {
    float a = gg[tid] * rsqrtf(gv[tid] + EPS);
    cstg[tid] = a; cstg[256 + tid] = gb[tid] - gm[tid] * a;
  }

  short8 arh[2], arl[2];
  short8 brh[4], brl[4];
  f32x4  acc[4][2];
#pragma unroll
  for (int i = 0; i < 4; ++i)
#pragma unroll
    for (int j = 0; j < 2; ++j) acc[i][j] = (f32x4){0.f, 0.f, 0.f, 0.f};

#define K3_PF(MAT) do {                                                       \
    const short* TH = (const short*)(ws + ((MAT) ? OFF_PHT_H : OFF_THT_H));   \
    const short* TL = (const short*)(ws + ((MAT) ? OFF_PHT_L : OFF_THT_L));   \
    _Pragma("unroll")                                                         \
    for (int p = 0; p < 2; ++p) {                                             \
      int q = tid + p * 256;                                                  \
      int sl = q >> 3, oct = q & 7;                                           \
      size_t ix = (size_t)(s0 + sl) * C_ + b * IC_ + oct * 8;                 \
      arh[p] = *(const short8*)&TH[ix];                                       \
      arl[p] = *(const short8*)&TL[ix];                                       \
    }                                                                         \
    _Pragma("unroll")                                                         \
    for (int p = 0; p < 4; ++p) {                                             \
      int q = tid + p * 256;                                                  \
      int o = q >> 3, oct = q & 7;                                            \
      size_t ix = ((size_t)(MAT) * IS_ + o_blk + o) * C_ + b * IC_ + oct * 8; \
      brh[p] = *(const short8*)&AH[ix];                                       \
      brl[p] = *(const short8*)&AL[ix];                                       \
    } } while (0)

  K3_PF(0);
  for (int c = 0; c < 2; ++c) {
    if (c) __syncthreads();
#pragma unroll
    for (int p = 0; p < 2; ++p) {
      int q = tid + p * 256;
      int sl = q >> 3, oct = q & 7;
      *(short8*)&th[sl * 72 + oct * 8]  = arh[p];
      *(short8*)&tlo[sl * 72 + oct * 8] = arl[p];
    }
#pragma unroll
    for (int p = 0; p < 4; ++p) {
      int q = tid + p * 256;
      int o = q >> 3, oct = q & 7;
      *(short8*)&ohh[o * 72 + oct * 8] = brh[p];
      *(short8*)&olo[o * 72 + oct * 8] = brl[p];
    }
    __syncthreads();
    if (c < 1) K3_PF(1);
#pragma unroll
    for (int ks = 0; ks < 2; ++ks) {
      const int ko = ks * 32 + ((lane >> 4) << 3);
      short8 ah[4], al[4], bh[2], bl[2];
#pragma unroll
      for (int si = 0; si < 4; ++si) {
        int r = (si * 16 + (lane & 15)) * 72 + ko;
        ah[si] = *(const short8*)&th[r];
        al[si] = *(const short8*)&tlo[r];
      }
#pragma unroll
      for (int oj = 0; oj < 2; ++oj) {
        int r = (wv * 32 + oj * 16 + (lane & 15)) * 72 + ko;
        bh[oj] = *(const short8*)&ohh[r];
        bl[oj] = *(const short8*)&olo[r];
      }
#pragma unroll
      for (int si = 0; si < 4; ++si)
#pragma unroll
        for (int oj = 0; oj < 2; ++oj) {
          acc[si][oj] = __builtin_amdgcn_mfma_f32_16x16x32_bf16(
              ah[si], bh[oj], acc[si][oj], 0, 0, 0);
          acc[si][oj] = __builtin_amdgcn_mfma_f32_16x16x32_bf16(
              ah[si], bl[oj], acc[si][oj], 0, 0, 0);
          acc[si][oj] = __builtin_amdgcn_mfma_f32_16x16x32_bf16(
              al[si], bh[oj], acc[si][oj], 0, 0, 0);
        }
    }
  }
#undef K3_PF
  short* g = (short*)(ws + OFF_G);
#pragma unroll
  for (int oj = 0; oj < 2; ++oj) {
    int o = o_blk + wv * 32 + oj * 16 + (lane & 15);
    float sc = cstg[o], bi = cstg[256 + o];
#pragma unroll
    for (int si = 0; si < 4; ++si) {
      int sq = s0 + si * 16 + ((lane >> 4) << 2);
      sh4 q4;
      q4[0] = f2bf(fmaxf(sc * acc[si][oj][0] + bi, 0.f));
      q4[1] = f2bf(fmaxf(sc * acc[si][oj][1] + bi, 0.f));
      q4[2] = f2bf(fmaxf(sc * acc[si][oj][2] + bi, 0.f));
      q4[3] = f2bf(fmaxf(sc * acc[si][oj][3] + bi, 0.f));
      *(sh4*)&g[((size_t)b * IS_ + o) * S_ + sq] = q4;
    }
  }
}

// --- k4: y=relu(bn(W1@g)); ys=bn(W2@y); gate=sigmoid; out = x*gate (fused)
// grid (64 s-tiles of 32, 8 b), 512 threads, ~56KB LDS -> 2 blocks/CU.
__global__ __launch_bounds__(512) void k4_fused(
    const float* __restrict__ x, const float* __restrict__ W1,
    const float* __restrict__ W2,
    const float* __restrict__ w1g, const float* __restrict__ w1b,
    const float* __restrict__ w1m, const float* __restrict__ w1v,
    const float* __restrict__ w2g, const float* __restrict__ w2b,
    const float* __restrict__ w2m, const float* __restrict__ w2v,
    const float* __restrict__ ws, float* __restrict__ out) {
  __shared__ float lds_g[128 * 36];    // 18.4 KB
  __shared__ float lds_w[32 * 260];    // 33.3 KB
  __shared__ float lds_y[32 * 33];     // 4.2 KB
  __shared__ float lds_gate[32];
  __shared__ float wc[66];             // w1 scale[32], w1 bias[32], w2 s/b
  const int tid = threadIdx.x;
  const int s0  = blockIdx.x * 32;
  const int b   = blockIdx.y;
  const int s   = tid & 31;
  const int og  = tid >> 5;            // 16 groups x 2 y-rows
  const short* gsrc = (const short*)(ws + OFF_G) + (size_t)b * IS_ * S_;

  if (tid < 32) {
    float a = w1g[tid] * rsqrtf(w1v[tid] + EPS);
    wc[tid] = a; wc[32 + tid] = w1b[tid] - w1m[tid] * a;
  } else if (tid == 32) {
    float a = w2g[0] * rsqrtf(w2v[0] + EPS);
    wc[64] = a; wc[65] = w2b[0] - w2m[0] * a;
  }
  // stage W1 [32][256] -> lds_w pitch 260 (one-time, 4 float4/thread)
#pragma unroll
  for (int j = 0; j < 4; ++j) {
    int f = tid + j * 512;             // 0..2047 float4 slots (32 rows x 64)
    int row = f >> 6, c4 = f & 63;
    *(float4*)&lds_w[row * 260 + c4 * 4] =
        *(const float4*)&W1[(size_t)row * IS_ + c4 * 4];
  }
  float acc[2] = {};

  for (int half = 0; half < 2; ++half) {
    __syncthreads();
    {
      int row = tid >> 2, oct = tid & 3;   // 128 rows x 4 octs = 512
      short8 v = *(const short8*)&gsrc[(size_t)(half * 128 + row) * S_ +
                                       s0 + oct * 8];
      float4 f0 = make_float4(bf2f(v[0]), bf2f(v[1]), bf2f(v[2]), bf2f(v[3]));
      float4 f1 = make_float4(bf2f(v[4]), bf2f(v[5]), bf2f(v[6]), bf2f(v[7]));
      *(float4*)&lds_g[row * 36 + oct * 8]     = f0;
      *(float4*)&lds_g[row * 36 + oct * 8 + 4] = f1;
    }
    __syncthreads();
#pragma unroll
    for (int c4 = 0; c4 < 32; ++c4) {
      float g0 = lds_g[(c4 * 4 + 0) * 36 + s];
      float g1 = lds_g[(c4 * 4 + 1) * 36 + s];
      float g2 = lds_g[(c4 * 4 + 2) * 36 + s];
      float g3 = lds_g[(c4 * 4 + 3) * 36 + s];
#pragma unroll
      for (int j = 0; j < 2; ++j) {
        const float4 w = *(const float4*)&lds_w[(og * 2 + j) * 260 +
                                                half * 128 + c4 * 4];
        acc[j] += g0 * w.x + g1 * w.y + g2 * w.z + g3 * w.w;
      }
    }
  }
#pragma unroll
  for (int j = 0; j < 2; ++j) {
    int o = og * 2 + j;
    float v = wc[o] * acc[j] + wc[32 + o];
    lds_y[o * 33 + s] = v > 0.f ? v : 0.f;
  }
  __syncthreads();
  if (tid < 32) {
    float sum = 0.f;
#pragma unroll
    for (int c = 0; c < 32; ++c) sum += W2[c] * lds_y[c * 33 + tid];
    float ys = wc[64] * sum + wc[65];
    lds_gate[tid] = 1.f / (1.f + expf(-ys));
  }
  __syncthreads();
  // stream: out[b][ch][s0..s0+31] = x * gate. 8-lane groups own one channel
  // row (128 B contiguous); wave covers 8 channels; 8 iters.
  const int l = tid & 63, w = tid >> 6;
  const int q4 = (l & 7) * 4;          // s-offset within tile
  const int cl = w * 8 + (l >> 3);     // channel-in-iteration 0..63
  const float4 gv = *(const float4*)&lds_gate[q4];
  const float* xb = x + (size_t)b * C_ * S_ + s0;
  float* ob = out + (size_t)b * C_ * S_ + s0;
#pragma unroll
  for (int it = 0; it < 8; ++it) {
    int ch = it * 64 + cl;
    const float4 xv = *(const float4*)&xb[(size_t)ch * S_ + q4];
    float4 ov;
    ov.x = xv.x * gv.x; ov.y = xv.y * gv.y;
    ov.z = xv.z * gv.z; ov.w = xv.w * gv.w;
    *(float4*)&ob[(size_t)ch * S_ + q4] = ov;
  }
}

// ---------------------------------------------------------------------------
extern "C" void kernel_launch(void* const* d_in, const int* in_sizes, int n_in,
                              void* d_out, int out_size, void* d_ws, size_t ws_size,
                              hipStream_t stream) {
  const float* x   = (const float*)d_in[0];
  const float* Wt  = (const float*)d_in[1];
  const float* tg  = (const float*)d_in[2];
  const float* tb  = (const float*)d_in[3];
  const float* tm  = (const float*)d_in[4];
  const float* tv  = (const float*)d_in[5];
  const float* Wp  = (const float*)d_in[6];
  const float* pg  = (const float*)d_in[7];
  const float* pb  = (const float*)d_in[8];
  const float* pm  = (const float*)d_in[9];
  const float* pv  = (const float*)d_in[10];
  const float* Wgg = (const float*)d_in[11];
  const float* ggg = (const float*)d_in[12];
  const float* ggb = (const float*)d_in[13];
  const float* ggm = (const float*)d_in[14];
  const float* ggv = (const float*)d_in[15];
  const float* W1  = (const float*)d_in[16];
  const float* w1g = (const float*)d_in[17];
  const float* w1b = (const float*)d_in[18];
  const float* w1m = (const float*)d_in[19];
  const float* w1v = (const float*)d_in[20];
  const float* W2  = (const float*)d_in[21];
  const float* w2g = (const float*)d_in[22];
  const float* w2b = (const float*)d_in[23];
  const float* w2m = (const float*)d_in[24];
  const float* w2v = (const float*)d_in[25];
  float* ws  = (float*)d_ws;
  float* out = (float*)d_out;

  k1_mfma<<<dim3(32, 8), 512, 0, stream>>>(
      x, Wt, Wp, tg, tb, tm, tv, pg, pb, pm, pv, ws);
  k2_mfma<<<dim3(8, 2, 16), 256, 0, stream>>>(Wgg, ws, ws + OFF_AP);
  k2b_reduce<<<256, 256, 0, stream>>>(ws);
  k3_mfma<<<dim3(32, 2, 8), 256, 0, stream>>>(ws, ggg, ggb, ggm, ggv);
  k4_fused<<<dim3(64, 8), 512, 0, stream>>>(
      x, W1, W2, w1g, w1b, w1m, w1v, w2g, w2b, w2m, w2v, ws, out);
}